// Round 1
// baseline (293.722 us; speedup 1.0000x reference)
//
#include <hip/hip_runtime.h>
#include <math.h>

#define kB 4
#define kC 8
#define kH 384
#define kW 384
#define kCH (kC * kH)   // 3072
#define kIN (2 * kCH)   // 6144
#define kNC 18
#define kMID (kW / 2)

// K1: faithful left/right from acquired_mask (jnp.argmax semantics: first True, 0 if none)
__global__ void mask_kernel(const float* __restrict__ am, int* __restrict__ lr,
                            float* __restrict__ heat) {
    int b = blockIdx.x, tid = threadIdx.x;
    __shared__ int sL[256], sR[256];
    int candR = 0x7fffffff, candL = 0x7fffffff;
    for (int i = tid; i < kW - kMID; i += 256)
        if (am[b * kW + kMID + i] < 1.0f) candR = min(candR, i);
    for (int i = tid; i < kMID; i += 256)
        if (am[b * kW + (kMID - 1 - i)] < 1.0f) candL = min(candL, i);
    sL[tid] = candL; sR[tid] = candR;
    __syncthreads();
    for (int s = 128; s > 0; s >>= 1) {
        if (tid < s) {
            sL[tid] = min(sL[tid], sL[tid + s]);
            sR[tid] = min(sR[tid], sR[tid + s]);
        }
        __syncthreads();
    }
    if (tid == 0) {
        int r = (sR[0] == 0x7fffffff) ? 0 : sR[0];
        int l = (sL[0] == 0x7fffffff) ? 0 : sL[0];
        lr[2 * b] = l + 1;       // left = argmax + 1
        lr[2 * b + 1] = kMID + r;  // right = mid + argmax
    }
    for (int i = tid; i < kW; i += 256) heat[b * kW + i] = 0.0f;
}

// K2: per needed column, Pq = Fq . W1[:, :CH]^T  and  Pa = Fa . W1[:, CH:]^T
__global__ void proj_kernel(const float* __restrict__ acquired,
                            const float* __restrict__ acquiring,
                            const float* __restrict__ qmask,
                            const float* __restrict__ W1,
                            const int* __restrict__ lr,
                            float* __restrict__ Pq, float* __restrict__ Pa) {
    int w = blockIdx.x, b = blockIdx.y, tid = threadIdx.x;
    int left = lr[2 * b], right = lr[2 * b + 1];
    bool need_a = (w >= left) && (w < right);
    bool need_q = (qmask[b * kW + w] > 0.0f);
    if (!need_a && !need_q) return;
    __shared__ float red[4][kNC];
    for (int half = 0; half < 2; ++half) {
        bool need = half ? need_a : need_q;
        if (!need) continue;
        const float* ks = half ? acquired : acquiring;
        const float* w1 = W1 + (half ? kCH : 0);
        float acc[kNC];
#pragma unroll
        for (int j = 0; j < kNC; ++j) acc[j] = 0.0f;
        for (int i = tid; i < kCH; i += 256) {
            // feature i = c*H + h ; flat row index b*CH + i ; column w, (re,im) pair
            const float2 v = *reinterpret_cast<const float2*>(
                ks + ((size_t)(b * kCH + i) * kW + w) * 2);
            float f = sqrtf(v.x * v.x + v.y * v.y);
#pragma unroll
            for (int j = 0; j < kNC; ++j) acc[j] = fmaf(f, w1[j * kIN + i], acc[j]);
        }
#pragma unroll
        for (int j = 0; j < kNC; ++j) {
            for (int off = 32; off > 0; off >>= 1) acc[j] += __shfl_down(acc[j], off, 64);
        }
        int wave = tid >> 6, lane = tid & 63;
        if (lane == 0) {
#pragma unroll
            for (int j = 0; j < kNC; ++j) red[wave][j] = acc[j];
        }
        __syncthreads();
        if (tid < kNC) {
            float s = red[0][tid] + red[1][tid] + red[2][tid] + red[3][tid];
            (half ? Pa : Pq)[((size_t)(b * kW + w)) * kNC + tid] = s;
        }
        __syncthreads();
    }
}

// K3: for each acquiring column w_i: heat = mean over w_c in [left,right) of
//     sigmoid(W4 . relu(W3 . relu(W2 . relu(Pq+Pa+b1) + b2) + b3) + b4)
__global__ void pair_kernel(const float* __restrict__ Pq, const float* __restrict__ Pa,
                            const float* __restrict__ qmask, const int* __restrict__ lr,
                            const float* __restrict__ b1, const float* __restrict__ W2,
                            const float* __restrict__ b2, const float* __restrict__ W3,
                            const float* __restrict__ b3, const float* __restrict__ W4,
                            const float* __restrict__ b4, float* __restrict__ heat) {
    int wi = blockIdx.x, b = blockIdx.y, tid = threadIdx.x;
    if (!(qmask[b * kW + wi] > 0.0f)) return;
    int left = lr[2 * b], right = lr[2 * b + 1];
    __shared__ float sW2[kNC * kNC], sW3[kNC * kNC], sW4[kNC];
    __shared__ float sb1[kNC], sb2[kNC], sb3[kNC], sPq[kNC];
    __shared__ float sb4, wred[4];
    for (int i = tid; i < kNC * kNC; i += 256) { sW2[i] = W2[i]; sW3[i] = W3[i]; }
    if (tid < kNC) {
        sW4[tid] = W4[tid]; sb1[tid] = b1[tid]; sb2[tid] = b2[tid]; sb3[tid] = b3[tid];
        sPq[tid] = Pq[((size_t)(b * kW + wi)) * kNC + tid];
    }
    if (tid == 0) sb4 = b4[0];
    __syncthreads();
    float ssum = 0.0f;
    for (int wc = left + tid; wc < right; wc += 256) {
        const float* pa = Pa + (size_t)(b * kW + wc) * kNC;
        float x[kNC], y[kNC];
#pragma unroll
        for (int j = 0; j < kNC; ++j) x[j] = fmaxf(sPq[j] + pa[j] + sb1[j], 0.0f);
#pragma unroll
        for (int k = 0; k < kNC; ++k) {
            float t = sb2[k];
#pragma unroll
            for (int j = 0; j < kNC; ++j) t = fmaf(sW2[k * kNC + j], x[j], t);
            y[k] = fmaxf(t, 0.0f);
        }
#pragma unroll
        for (int k = 0; k < kNC; ++k) {
            float t = sb3[k];
#pragma unroll
            for (int j = 0; j < kNC; ++j) t = fmaf(sW3[k * kNC + j], y[j], t);
            x[k] = fmaxf(t, 0.0f);
        }
        float t = sb4;
#pragma unroll
        for (int j = 0; j < kNC; ++j) t = fmaf(sW4[j], x[j], t);
        ssum += 1.0f / (1.0f + expf(-t));
    }
    for (int off = 32; off > 0; off >>= 1) ssum += __shfl_down(ssum, off, 64);
    int wave = tid >> 6, lane = tid & 63;
    if (lane == 0) wred[wave] = ssum;
    __syncthreads();
    if (tid == 0) {
        float total = wred[0] + wred[1] + wred[2] + wred[3];
        heat[b * kW + wi] = total / (float)(right - left);
    }
}

// K4: broadcast heat over H into [B,H,W] output (coalesced)
__global__ void out_kernel(const float* __restrict__ heat, float* __restrict__ out) {
    int idx = blockIdx.x * 256 + threadIdx.x;
    if (idx < kB * kH * kW) {
        int w = idx % kW;
        int b = idx / (kH * kW);
        out[idx] = heat[b * kW + w];
    }
}

extern "C" void kernel_launch(void* const* d_in, const int* in_sizes, int n_in,
                              void* d_out, int out_size, void* d_ws, size_t ws_size,
                              hipStream_t stream) {
    const float* acquired       = (const float*)d_in[0];
    const float* acquiring      = (const float*)d_in[1];
    const float* acquired_mask  = (const float*)d_in[2];
    const float* acquiring_mask = (const float*)d_in[3];
    const float* W1 = (const float*)d_in[4];
    const float* b1 = (const float*)d_in[5];
    const float* W2 = (const float*)d_in[6];
    const float* b2 = (const float*)d_in[7];
    const float* W3 = (const float*)d_in[8];
    const float* b3 = (const float*)d_in[9];
    const float* W4 = (const float*)d_in[10];
    const float* b4 = (const float*)d_in[11];
    float* out = (float*)d_out;

    int*   lr   = (int*)d_ws;                 // 2*B ints
    float* heat = (float*)d_ws + 8;           // B*W floats
    float* Pq   = heat + kB * kW;             // B*W*18
    float* Pa   = Pq + (size_t)kB * kW * kNC; // B*W*18

    mask_kernel<<<kB, 256, 0, stream>>>(acquired_mask, lr, heat);
    proj_kernel<<<dim3(kW, kB), 256, 0, stream>>>(acquired, acquiring, acquiring_mask,
                                                  W1, lr, Pq, Pa);
    pair_kernel<<<dim3(kW, kB), 256, 0, stream>>>(Pq, Pa, acquiring_mask, lr,
                                                  b1, W2, b2, W3, b3, W4, b4, heat);
    int n = kB * kH * kW;
    out_kernel<<<(n + 255) / 256, 256, 0, stream>>>(heat, out);
}

// Round 2
// 249.972 us; speedup vs baseline: 1.1750x; 1.1750x over previous
//
#include <hip/hip_runtime.h>
#include <math.h>
#include <limits.h>

#define kB 4
#define kC 8
#define kH 384
#define kW 384
#define kCH (kC * kH)   // 3072
#define kIN (2 * kCH)   // 6144
#define kNC 18
#define kMID (kW / 2)

// Expand M(0)..M(17)
#define E18(M) M(0) M(1) M(2) M(3) M(4) M(5) M(6) M(7) M(8) M(9) M(10) M(11) M(12) M(13) M(14) M(15) M(16) M(17)

// --------------------------------------------------------------------------
// K1: per needed column, Pq = Fq . W1[:, :CH]^T  and  Pa = Fa . W1[:, CH:]^T
// left/right computed inline per block (L2-cached mask row, cheap).
// All MLP/accumulator state in explicit scalar registers — no local arrays.
// --------------------------------------------------------------------------
__global__ __launch_bounds__(256)
void proj_kernel(const float* __restrict__ acquired,
                 const float* __restrict__ acquiring,
                 const float* __restrict__ am,
                 const float* __restrict__ qmask,
                 const float* __restrict__ W1,
                 float* __restrict__ Pq, float* __restrict__ Pa) {
    int w = blockIdx.x, b = blockIdx.y, tid = threadIdx.x;

    // faithful left/right from acquired_mask (argmax(<1) semantics, 0 if none)
    __shared__ int sL[256], sR[256];
    int candR = INT_MAX, candL = INT_MAX;
    for (int i = tid; i < kW - kMID; i += 256)
        if (am[b * kW + kMID + i] < 1.0f) candR = min(candR, i);
    for (int i = tid; i < kMID; i += 256)
        if (am[b * kW + (kMID - 1 - i)] < 1.0f) candL = min(candL, i);
    sL[tid] = candL; sR[tid] = candR;
    __syncthreads();
    for (int s = 128; s > 0; s >>= 1) {
        if (tid < s) {
            sL[tid] = min(sL[tid], sL[tid + s]);
            sR[tid] = min(sR[tid], sR[tid + s]);
        }
        __syncthreads();
    }
    int left  = ((sL[0] == INT_MAX) ? 0 : sL[0]) + 1;
    int right = kMID + ((sR[0] == INT_MAX) ? 0 : sR[0]);

    bool need_a = (w >= left) && (w < right);
    bool need_q = (qmask[b * kW + w] > 0.0f);
    if (!need_a && !need_q) return;

    __shared__ float red[4][kNC];
    for (int half = 0; half < 2; ++half) {
        bool need = half ? need_a : need_q;
        if (!need) continue;
        const float* ks = half ? acquired : acquiring;
        const float* w1 = W1 + (half ? kCH : 0);

#define DECLACC(j) float a##j = 0.0f;
        E18(DECLACC)

        for (int i = tid; i < kCH; i += 256) {
            const float2 v = *reinterpret_cast<const float2*>(
                ks + ((size_t)(b * kCH + i) * kW + w) * 2);
            float f = sqrtf(v.x * v.x + v.y * v.y);
#define ACC(j) a##j = fmaf(f, w1[(j) * kIN + i], a##j);
            E18(ACC)
        }

#define RED(j) { a##j += __shfl_down(a##j, 32, 64); a##j += __shfl_down(a##j, 16, 64); \
                 a##j += __shfl_down(a##j,  8, 64); a##j += __shfl_down(a##j,  4, 64); \
                 a##j += __shfl_down(a##j,  2, 64); a##j += __shfl_down(a##j,  1, 64); }
        E18(RED)

        int wave = tid >> 6, lane = tid & 63;
        if (lane == 0) {
#define STOREW(j) red[wave][j] = a##j;
            E18(STOREW)
        }
        __syncthreads();
        if (tid < kNC) {
            float s = red[0][tid] + red[1][tid] + red[2][tid] + red[3][tid];
            (half ? Pa : Pq)[((size_t)(b * kW + w)) * kNC + tid] = s;
        }
        __syncthreads();
    }
}

// --------------------------------------------------------------------------
// K2: for each (b, wi): if acquiring, heat = mean over wc in [left,right) of
// sigmoid(W4.relu(W3.relu(W2.relu(Pq+Pa+b1)+b2)+b3)+b4); write column wi of
// out[B,H,W] (zeros for non-acquiring columns). Fully scalarized MLP.
// --------------------------------------------------------------------------
__global__ __launch_bounds__(256)
void pair_kernel(const float* __restrict__ Pq, const float* __restrict__ Pa,
                 const float* __restrict__ am, const float* __restrict__ qmask,
                 const float* __restrict__ b1, const float* __restrict__ W2,
                 const float* __restrict__ b2, const float* __restrict__ W3,
                 const float* __restrict__ b3, const float* __restrict__ W4,
                 const float* __restrict__ b4, float* __restrict__ out) {
    int wi = blockIdx.x, b = blockIdx.y, tid = threadIdx.x;

    bool active = (qmask[b * kW + wi] > 0.0f);
    if (!active) {  // block-uniform
        for (int h = tid; h < kH; h += 256)
            out[((size_t)b * kH + h) * kW + wi] = 0.0f;
        return;
    }

    // left/right inline
    __shared__ int sL[256], sR[256];
    int candR = INT_MAX, candL = INT_MAX;
    for (int i = tid; i < kW - kMID; i += 256)
        if (am[b * kW + kMID + i] < 1.0f) candR = min(candR, i);
    for (int i = tid; i < kMID; i += 256)
        if (am[b * kW + (kMID - 1 - i)] < 1.0f) candL = min(candL, i);
    sL[tid] = candL; sR[tid] = candR;
    __syncthreads();
    for (int s = 128; s > 0; s >>= 1) {
        if (tid < s) {
            sL[tid] = min(sL[tid], sL[tid + s]);
            sR[tid] = min(sR[tid], sR[tid + s]);
        }
        __syncthreads();
    }
    int left  = ((sL[0] == INT_MAX) ? 0 : sL[0]) + 1;
    int right = kMID + ((sR[0] == INT_MAX) ? 0 : sR[0]);

    __shared__ float sW2[kNC * kNC], sW3[kNC * kNC], sW4[kNC];
    __shared__ float sb1[kNC], sb2[kNC], sb3[kNC], sPq[kNC];
    __shared__ float sb4, wred[4];
    for (int i = tid; i < kNC * kNC; i += 256) { sW2[i] = W2[i]; sW3[i] = W3[i]; }
    if (tid < kNC) {
        sW4[tid] = W4[tid]; sb1[tid] = b1[tid]; sb2[tid] = b2[tid]; sb3[tid] = b3[tid];
        sPq[tid] = Pq[((size_t)(b * kW + wi)) * kNC + tid];
    }
    if (tid == 0) sb4 = b4[0];
    __syncthreads();

#define DOTX(Wm, r) (Wm[(r)*kNC+ 0]*x0 + Wm[(r)*kNC+ 1]*x1 + Wm[(r)*kNC+ 2]*x2 + \
                     Wm[(r)*kNC+ 3]*x3 + Wm[(r)*kNC+ 4]*x4 + Wm[(r)*kNC+ 5]*x5 + \
                     Wm[(r)*kNC+ 6]*x6 + Wm[(r)*kNC+ 7]*x7 + Wm[(r)*kNC+ 8]*x8 + \
                     Wm[(r)*kNC+ 9]*x9 + Wm[(r)*kNC+10]*x10 + Wm[(r)*kNC+11]*x11 + \
                     Wm[(r)*kNC+12]*x12 + Wm[(r)*kNC+13]*x13 + Wm[(r)*kNC+14]*x14 + \
                     Wm[(r)*kNC+15]*x15 + Wm[(r)*kNC+16]*x16 + Wm[(r)*kNC+17]*x17)
#define DOTY(Wm, r) (Wm[(r)*kNC+ 0]*y0 + Wm[(r)*kNC+ 1]*y1 + Wm[(r)*kNC+ 2]*y2 + \
                     Wm[(r)*kNC+ 3]*y3 + Wm[(r)*kNC+ 4]*y4 + Wm[(r)*kNC+ 5]*y5 + \
                     Wm[(r)*kNC+ 6]*y6 + Wm[(r)*kNC+ 7]*y7 + Wm[(r)*kNC+ 8]*y8 + \
                     Wm[(r)*kNC+ 9]*y9 + Wm[(r)*kNC+10]*y10 + Wm[(r)*kNC+11]*y11 + \
                     Wm[(r)*kNC+12]*y12 + Wm[(r)*kNC+13]*y13 + Wm[(r)*kNC+14]*y14 + \
                     Wm[(r)*kNC+15]*y15 + Wm[(r)*kNC+16]*y16 + Wm[(r)*kNC+17]*y17)

    float ssum = 0.0f;
    for (int wc = left + tid; wc < right; wc += 256) {
        const float* pa = Pa + (size_t)(b * kW + wc) * kNC;
#define DX(i) float x##i = fmaxf(sPq[i] + pa[i] + sb1[i], 0.0f);
        E18(DX)
#define DY(i) float y##i = fmaxf(sb2[i] + DOTX(sW2, i), 0.0f);
        E18(DY)
#define DZ(i) float z##i = fmaxf(sb3[i] + DOTY(sW3, i), 0.0f);
        E18(DZ)
        float t = sb4 +
            (sW4[0]*z0 + sW4[1]*z1 + sW4[2]*z2 + sW4[3]*z3 + sW4[4]*z4 + sW4[5]*z5 +
             sW4[6]*z6 + sW4[7]*z7 + sW4[8]*z8 + sW4[9]*z9 + sW4[10]*z10 + sW4[11]*z11 +
             sW4[12]*z12 + sW4[13]*z13 + sW4[14]*z14 + sW4[15]*z15 + sW4[16]*z16 + sW4[17]*z17);
        ssum += 1.0f / (1.0f + expf(-t));
    }

    ssum += __shfl_down(ssum, 32, 64); ssum += __shfl_down(ssum, 16, 64);
    ssum += __shfl_down(ssum,  8, 64); ssum += __shfl_down(ssum,  4, 64);
    ssum += __shfl_down(ssum,  2, 64); ssum += __shfl_down(ssum,  1, 64);
    int wave = tid >> 6, lane = tid & 63;
    if (lane == 0) wred[wave] = ssum;
    __syncthreads();
    float val = (wred[0] + wred[1] + wred[2] + wred[3]) / (float)(right - left);
    for (int h = tid; h < kH; h += 256)
        out[((size_t)b * kH + h) * kW + wi] = val;
}

extern "C" void kernel_launch(void* const* d_in, const int* in_sizes, int n_in,
                              void* d_out, int out_size, void* d_ws, size_t ws_size,
                              hipStream_t stream) {
    const float* acquired       = (const float*)d_in[0];
    const float* acquiring      = (const float*)d_in[1];
    const float* acquired_mask  = (const float*)d_in[2];
    const float* acquiring_mask = (const float*)d_in[3];
    const float* W1 = (const float*)d_in[4];
    const float* b1 = (const float*)d_in[5];
    const float* W2 = (const float*)d_in[6];
    const float* b2 = (const float*)d_in[7];
    const float* W3 = (const float*)d_in[8];
    const float* b3 = (const float*)d_in[9];
    const float* W4 = (const float*)d_in[10];
    const float* b4 = (const float*)d_in[11];
    float* out = (float*)d_out;

    float* Pq = (float*)d_ws;                   // B*W*18
    float* Pa = Pq + (size_t)kB * kW * kNC;     // B*W*18

    proj_kernel<<<dim3(kW, kB), 256, 0, stream>>>(acquired, acquiring, acquired_mask,
                                                  acquiring_mask, W1, Pq, Pa);
    pair_kernel<<<dim3(kW, kB), 256, 0, stream>>>(Pq, Pa, acquired_mask, acquiring_mask,
                                                  b1, W2, b2, W3, b3, W4, b4, out);
}